// Round 4
// baseline (394.111 us; speedup 1.0000x reference)
//
#include <hip/hip_runtime.h>
#include <hip/hip_bf16.h>
#include <cmath>

// ---------------------------------------------------------------------------
// TransformerEncoderLayer, fp32 in/out (bf16 MFMA internally), MI355X gfx950.
// Pipeline: 4x weight-transpose(f32->bf16T) -> LN1 -> GEMM256n(qkv,scatter)
//           -> flash-attn -> GEMM64(proj,+x -> f32 x2) -> LN2
//           -> GEMM256n(fc1,GELU) -> GEMM64(fc2,+x2 -> f32 out)
// v7: 3-deep counted-vmcnt prefetch (T4 without the 8-phase split).
// Diagnosis R1-R3: the 2-phase loop's __syncthreads drains vmcnt(0) for a
// tile issued only one compute-phase (~300cy) earlier vs ~600-900cy latency
// -> every iteration pays the residual. R3's 16-barrier 8-phase made it
// worse. Fix: ONE {s_waitcnt vmcnt(6); s_barrier} per iteration, 3 LDS
// buffers, stage issued 2 tiles ahead. Hazards (verified by hand):
//   RAW: own tile-kb loads forced by vmcnt(6) (12 outstanding -> oldest 6);
//        other waves' by their vmcnt+barrier. Last iter uses vmcnt(0)
//        (vmcnt(6) would pass vacuously -> race).
//   WAR: stage(kb+2) overwrites the buffer whose last ds_read completed
//        before its reader's MFMAs, which precede barrier arrival.
// gemm256n_k (qkv/fc1): 256x128 tile, BK=64, 8 waves, 144KB LDS, 1 blk/CU.
// gemm64_k (proj/fc2): 128x64 tile, BK=64, 4 waves, NBUF=3 (72KB, 2 blk/CU),
//   n-based XCD remap -> each XCD's B-slice (1MB @fc2) is L2-resident.
// Attention v4 (unchanged, proven 63us): XCD remap, exp2 folded scale.
// ---------------------------------------------------------------------------

typedef __hip_bfloat16 bf16;
typedef __bf16 bf16x8 __attribute__((ext_vector_type(8)));
typedef __bf16 bf16x4v __attribute__((ext_vector_type(4)));
typedef float  f32x4  __attribute__((ext_vector_type(4)));

#define CB 2
#define CN 2048
#define CE 1024
#define CH 16
#define CD 64
#define CMLP 4096
#define CM (CB*CN)   // 4096 tokens

#define PS 136       // attn P-tile LDS row stride (elems)

#define EXP2F exp2f
#define SM_SCALE_LOG2E 0.18033688011112042f   // 0.125 * log2(e)

__device__ __forceinline__ float b2f(bf16 v){ return __bfloat162float(v); }
__device__ __forceinline__ bf16  f2b(float v){ return __float2bfloat16(v); }

__device__ __forceinline__ void gl_lds16(const void* g, void* l){
  __builtin_amdgcn_global_load_lds((__attribute__((address_space(1))) void*)g,
                                   (__attribute__((address_space(3))) void*)l,
                                   16, 0, 0);
}

#define FENCE asm volatile("" ::: "memory")
#define BAR   do{ FENCE; __builtin_amdgcn_s_barrier(); FENCE; }while(0)
#define VMW6  asm volatile("s_waitcnt vmcnt(6)" ::: "memory")
#define VMW0  asm volatile("s_waitcnt vmcnt(0)" ::: "memory")

// in: f32 [K,N] row-major -> out: bf16 [N,K] row-major
__global__ __launch_bounds__(256) void transpose_k(const float* __restrict__ in,
                                                   bf16* __restrict__ out,
                                                   int K, int N){
  __shared__ float tile[32][33];
  const int n0 = blockIdx.x*32, k0 = blockIdx.y*32;
  const int tx = threadIdx.x & 31;
  const int ty = threadIdx.x >> 5;   // 0..7
  #pragma unroll
  for(int i=0;i<32;i+=8) tile[ty+i][tx] = in[(size_t)(k0+ty+i)*N + n0+tx];
  __syncthreads();
  #pragma unroll
  for(int i=0;i<32;i+=8) out[(size_t)(n0+ty+i)*K + k0+tx] = f2b(tile[tx][ty+i]);
}

// LayerNorm: one row (E=1024) per 256-thread block; f32 in -> bf16 out
__global__ __launch_bounds__(256) void ln_k(const float* __restrict__ x,
                                            const float* __restrict__ g,
                                            const float* __restrict__ be,
                                            bf16* __restrict__ out){
  const int row = blockIdx.x;
  const int t = threadIdx.x;
  const float4 v4 = ((const float4*)(x + (size_t)row*CE))[t];
  float v[4] = {v4.x, v4.y, v4.z, v4.w};
  float s=0.f, s2=0.f;
  #pragma unroll
  for(int i=0;i<4;i++){ s+=v[i]; s2+=v[i]*v[i]; }
  #pragma unroll
  for(int off=32; off>0; off>>=1){ s += __shfl_down(s,off); s2 += __shfl_down(s2,off); }
  __shared__ float red[8];
  __shared__ float mu_s, rs_s;
  const int wv=t>>6, ln=t&63;
  if(ln==0){ red[wv]=s; red[4+wv]=s2; }
  __syncthreads();
  if(t==0){
    float S=red[0]+red[1]+red[2]+red[3], S2=red[4]+red[5]+red[6]+red[7];
    float mu=S/CE;
    mu_s=mu; rs_s=rsqrtf(S2/CE - mu*mu + 1e-5f);
  }
  __syncthreads();
  const float mu=mu_s, rs=rs_s;
  #pragma unroll
  for(int i=0;i<4;i++){
    int c=t*4+i;
    out[(size_t)row*CE+c] = f2b((v[i]-mu)*rs*g[c] + be[c]);
  }
}

#define EP_QKV 0
#define EP_GELU 2

// ---------------------------------------------------------------------------
// gemm256n_k: C = A[M,K]*BT[N,K]^T, tile 256x128, BK=64, 512 thr (8 waves,
// 2m x 4n; per-wave 128x32 = acc[8][2]). LDS 3 x (32KB A + 16KB B) = 144KB.
// 3-deep counted-vmcnt loop (see header). Launch grid dim3(16, N/128):
// lin = bx + 16*by; m_idx = lin&15 (XCD c holds m-panels {c, c+8}),
// n_idx = lin>>4.
// ---------------------------------------------------------------------------
template<int MODE>
__global__ __launch_bounds__(512,1) void gemm256n_k(
  const bf16* __restrict__ A, const bf16* __restrict__ BT,
  const float* __restrict__ bias,
  bf16* __restrict__ Cb, bf16* __restrict__ Cq, bf16* __restrict__ Ck,
  bf16* __restrict__ Cv, int Ksz, int Nsz)
{
  __shared__ __align__(16) bf16 Alds[3][256*64];   // 32KB per buf
  __shared__ __align__(16) bf16 Blds[3][128*64];   // 16KB per buf
  const int tid = threadIdx.x;
  const int wave = tid>>6, lane = tid&63;
  const int m16 = lane&15, quad = lane>>4;
  const int sw = m16&7;
  const int wi = wave>>2, wj = wave&3;      // 2 x 4 wave grid

  const int lin = blockIdx.x + gridDim.x*blockIdx.y;
  const int m_idx = lin&15;
  const int n_idx = lin>>4;
  const size_t m0 = (size_t)m_idx*256;
  const size_t n0 = (size_t)n_idx*128;

  f32x4 acc[8][2] = {};

  // staging: wave covers A rows [wave*32, wave*32+32) (4 instrs x 8 rows)
  // and B rows [wave*16, wave*16+16) (2 instrs); XOR-swizzled source chunk
  // (LDS slot s of row r holds global chunk s^(r&7)).
  const int srow8 = lane>>3;
  const int schk  = ((lane&7)^srow8)*8;
  const bf16* pA = A  + (m0 + 32*wave + srow8)*(size_t)Ksz + schk;
  const bf16* pB = BT + (n0 + 16*wave + srow8)*(size_t)Ksz + schk;

  auto stage = [&](int buf, size_t ko){
    bf16* lA = &Alds[buf][wave*2048];
    bf16* lB = &Blds[buf][wave*1024];
    #pragma unroll
    for(int j=0;j<4;j++) gl_lds16(pA + ko + (size_t)(j*8)*Ksz, lA + j*512);
    #pragma unroll
    for(int j=0;j<2;j++) gl_lds16(pB + ko + (size_t)(j*8)*Ksz, lB + j*512);
  };
  auto compute = [&](int buf){
    #pragma unroll
    for(int w=0;w<2;w++){
      bf16x8 af[8], bfr[2];
      #pragma unroll
      for(int i=0;i<8;i++)
        af[i] = *(const bf16x8*)(&Alds[buf][(wi*128+16*i+m16)*64 + ((w*4+quad)^sw)*8]);
      #pragma unroll
      for(int j=0;j<2;j++)
        bfr[j] = *(const bf16x8*)(&Blds[buf][(wj*32+16*j+m16)*64 + ((w*4+quad)^sw)*8]);
      #pragma unroll
      for(int i=0;i<8;i++)
        #pragma unroll
        for(int j=0;j<2;j++)
          acc[i][j] = __builtin_amdgcn_mfma_f32_16x16x32_bf16(af[i], bfr[j], acc[i][j], 0,0,0);
    }
  };

  const int kIters = Ksz/64;          // >= 2 (here 16)
  stage(0, 0); stage(1, 64);
  size_t ko = 128;
  int bc = 0, bs = 2;
  for(int kb=0; kb<kIters; ++kb){
    if(kb==kIters-1){ VMW0; } else { VMW6; }   // force own tile-kb loads
    BAR;                                        // -> all waves' tile kb landed
    if(kb+2<kIters){ stage(bs, ko); ko += 64; }
    compute(bc);
    bc = (bc==2)?0:bc+1;
    bs = (bs==2)?0:bs+1;
  }

  // epilogue: row = m0+wi*128+16i+quad*4+r, col = n0+wj*32+16j+m16
  #pragma unroll
  for(int i=0;i<8;i++){
    #pragma unroll
    for(int j=0;j<2;j++){
      const int col = (int)n0 + wj*32 + 16*j + m16;
      const float bcol = bias[col];
      #pragma unroll
      for(int r=0;r<4;r++){
        const int row = (int)m0 + wi*128 + 16*i + quad*4 + r;
        float v = acc[i][j][r] + bcol;
        if constexpr (MODE==EP_QKV){
          const int b = row>>11, n = row&2047;
          const int which = col>>10, cc = col&1023;
          const int h = cc>>6, d = cc&63;
          if(which==0)      Cq[(((size_t)(b*CH+h))*CN+n)*CD + d] = f2b(v);
          else if(which==1) Ck[(((size_t)(b*CH+h))*CN+n)*CD + d] = f2b(v);
          else              Cv[(((size_t)(b*CH+h))*CD+d)*CN + n] = f2b(v);
        } else { // EP_GELU: tanh-form, branch-free.
          const float u2 = 1.5957691216f*(v + 0.044715f*v*v*v);
          v = v * (1.f/(1.f + __expf(-u2)));
          Cb[(size_t)row*Nsz+col] = f2b(v);
        }
      }
    }
  }
}

// ---------------------------------------------------------------------------
// gemm64_k: C = A[M,K]*BT[N,K]^T + bias + res (f32 out), tile 128x64, BK=64,
// 256 thr (4 waves, 2m x 2n; per-wave 64x32 = acc[4][2]). NBUF=3 (72KB LDS,
// 2 blk/CU), 3-deep counted-vmcnt loop. n-based XCD remap: XCD c owns
// n_idx {2c, 2c+1} -> its B-slice (128 rows x K) stays L2-resident.
// Launch grid dim3(16, 32): lin = bx + 16*by.
// ---------------------------------------------------------------------------
__global__ __launch_bounds__(256,2) void gemm64_k(
  const bf16* __restrict__ A, const bf16* __restrict__ BT,
  const float* __restrict__ bias, const float* __restrict__ res,
  float* __restrict__ Cf, int Ksz, int Nsz)
{
  __shared__ __align__(16) bf16 Alds[3][128*64];   // 16KB per buf
  __shared__ __align__(16) bf16 Blds[3][64*64];    // 8KB per buf
  const int tid = threadIdx.x;
  const int wave = tid>>6, lane = tid&63;
  const int m16 = lane&15, quad = lane>>4;
  const int wi = wave>>1, wj = wave&1;

  const int lin = blockIdx.x + gridDim.x*blockIdx.y;
  const int n_idx = (lin&7)*2 + ((lin>>3)&1);   // 0..15, XCD-resident pair
  const int m_idx = lin>>4;                     // 0..31
  const size_t m0 = (size_t)m_idx*128;
  const size_t n0 = (size_t)n_idx*64;

  f32x4 acc[4][2] = {};

  const int srow8 = lane>>3;
  const int schk  = ((lane&7)^srow8)*8;
  const bf16* pA = A  + (m0 + 32*wave + srow8)*(size_t)Ksz + schk;
  const bf16* pB = BT + (n0 + 16*wave + srow8)*(size_t)Ksz + schk;

  auto stage = [&](int buf, size_t ko){
    bf16* lA = &Alds[buf][wave*2048];
    bf16* lB = &Blds[buf][wave*1024];
    #pragma unroll
    for(int j=0;j<4;j++) gl_lds16(pA + ko + (size_t)(j*8)*Ksz, lA + j*512);
    #pragma unroll
    for(int j=0;j<2;j++) gl_lds16(pB + ko + (size_t)(j*8)*Ksz, lB + j*512);
  };
  auto compute = [&](int buf){
    #pragma unroll
    for(int w=0;w<2;w++){
      const int swl = (m16&7);
      bf16x8 af[4], bfr[2];
      #pragma unroll
      for(int i=0;i<4;i++){
        const int row = wi*64+16*i+m16;
        af[i] = *(const bf16x8*)(&Alds[buf][row*64 + ((w*4+quad)^swl)*8]);
      }
      #pragma unroll
      for(int j=0;j<2;j++){
        const int row = wj*32+16*j+m16;
        bfr[j] = *(const bf16x8*)(&Blds[buf][row*64 + ((w*4+quad)^swl)*8]);
      }
      #pragma unroll
      for(int i=0;i<4;i++)
        #pragma unroll
        for(int j=0;j<2;j++)
          acc[i][j] = __builtin_amdgcn_mfma_f32_16x16x32_bf16(af[i], bfr[j], acc[i][j], 0,0,0);
    }
  };

  const int kIters = Ksz/64;          // 16 (proj) or 64 (fc2)
  stage(0, 0); stage(1, 64);
  size_t ko = 128;
  int bc = 0, bs = 2;
  for(int kb=0; kb<kIters; ++kb){
    if(kb==kIters-1){ VMW0; } else { VMW6; }
    BAR;
    if(kb+2<kIters){ stage(bs, ko); ko += 64; }
    compute(bc);
    bc = (bc==2)?0:bc+1;
    bs = (bs==2)?0:bs+1;
  }

  #pragma unroll
  for(int i=0;i<4;i++){
    #pragma unroll
    for(int j=0;j<2;j++){
      const int col = (int)n0 + wj*32 + 16*j + m16;
      const float bcol = bias[col];
      #pragma unroll
      for(int r=0;r<4;r++){
        const int row = (int)m0 + wi*64 + 16*i + quad*4 + r;
        float v = acc[i][j][r] + bcol + res[(size_t)row*Nsz+col];
        Cf[(size_t)row*Nsz+col] = v;
      }
    }
  }
}

// Flash attention v4: grid (N/128, B*H) remapped so all 16 q-blocks of one
// (b,h) share lin%8 (same XCD -> K/V re-reads hit that XCD's L2).
__global__ __launch_bounds__(256,2) void attn_k(
  const bf16* __restrict__ Q, const bf16* __restrict__ Kx,
  const bf16* __restrict__ Vt, bf16* __restrict__ O)
{
  const int lin = blockIdx.x + gridDim.x*blockIdx.y;
  const int bh = (lin&7) + 8*(lin>>7);
  const int qblk = (lin>>3)&15;
  const int b = bh>>4, h = bh&15;
  const int tid = threadIdx.x;
  const int wave = tid>>6, lane = tid&63;
  const int m16 = lane&15, quad = lane>>4;
  const int sw = m16&7;
  const int q0 = qblk*128 + wave*32;

  const bf16* Qb = Q  + (size_t)bh*CN*CD;
  const bf16* Kb = Kx + (size_t)bh*CN*CD;
  const bf16* Vb = Vt + (size_t)bh*CD*CN;

  bf16x8 qf[2][2];
  #pragma unroll
  for(int g=0;g<2;g++){
    const bf16* qp = Qb + (size_t)(q0+g*16+m16)*CD + quad*8;
    qf[g][0] = *(const bf16x8*)(qp);
    qf[g][1] = *(const bf16x8*)(qp + 32);
  }

  float li[2] = {0.f, 0.f};
  f32x4 oacc[2][4] = {};

  __shared__ __align__(16) bf16 Klds[128*64];   // 16 KB
  __shared__ __align__(16) bf16 Vlds[64*128];   // 16 KB
  __shared__ __align__(16) bf16 Plds[4][32*PS]; // 34.8 KB
  bf16* Pw = &Plds[wave][0];

  const int krow = wave*32 + (lane>>3);
  const int kchk = (lane&7) ^ (lane>>3);
  const bf16* pK = Kb + (size_t)krow*CD + kchk*8;
  const int vrow = wave*16 + (lane>>4);
  const bf16* pV[4];
  #pragma unroll
  for(int j=0;j<4;j++){
    const int ck = (lane&15) ^ ((j*4 + (lane>>4)) & 7);
    pV[j] = Vb + (size_t)(vrow + j*4)*CN + ck*8;
  }
  bf16* lK = Klds + wave*2048;
  bf16* lV = Vlds + wave*2048;

  for(int kt=0; kt<CN; kt+=128){
    __syncthreads();
    #pragma unroll
    for(int j=0;j<4;j++){
      gl_lds16(pK + (size_t)j*8*CD, lK + j*512);
      gl_lds16(pV[j],               lV + j*512);
      pV[j] += 128;
    }
    pK += (size_t)128*CD;
    __syncthreads();

    f32x4 sf0[8], sf1[8];
    #pragma unroll
    for(int f=0;f<8;f++){
      const bf16* kb = Klds + (f*16+m16)*64;
      bf16x8 k0 = *(const bf16x8*)(kb + ((quad   ^ sw)*8));
      bf16x8 k1 = *(const bf16x8*)(kb + (((quad+4)^ sw)*8));
      f32x4 t0 = {}, t1 = {};
      t0 = __builtin_amdgcn_mfma_f32_16x16x32_bf16(k0, qf[0][0], t0, 0,0,0);
      t0 = __builtin_amdgcn_mfma_f32_16x16x32_bf16(k1, qf[0][1], t0, 0,0,0);
      t1 = __builtin_amdgcn_mfma_f32_16x16x32_bf16(k0, qf[1][0], t1, 0,0,0);
      t1 = __builtin_amdgcn_mfma_f32_16x16x32_bf16(k1, qf[1][1], t1, 0,0,0);
      sf0[f]=t0; sf1[f]=t1;
    }
    #pragma unroll
    for(int f=0;f<8;f++){
      bf16x4v p0, p1;
      #pragma unroll
      for(int r=0;r<4;r++){
        float e0 = EXP2F(sf0[f][r]*SM_SCALE_LOG2E); li[0]+=e0; p0[r]=(__bf16)e0;
        float e1 = EXP2F(sf1[f][r]*SM_SCALE_LOG2E); li[1]+=e1; p1[r]=(__bf16)e1;
      }
      *(bf16x4v*)(Pw + (size_t)m16*PS       + f*16 + quad*4) = p0;
      *(bf16x4v*)(Pw + (size_t)(16+m16)*PS  + f*16 + quad*4) = p1;
    }
    asm volatile("s_waitcnt lgkmcnt(0)" ::: "memory");
    #pragma unroll
    for(int c=0;c<4;c++){
      const bf16x8 ap0 = *(const bf16x8*)(Pw + (size_t)m16*PS      + c*32 + quad*8);
      const bf16x8 ap1 = *(const bf16x8*)(Pw + (size_t)(16+m16)*PS + c*32 + quad*8);
      #pragma unroll
      for(int dt=0;dt<4;dt++){
        const int d = dt*16+m16;
        bf16x8 bv = *(const bf16x8*)(Vlds + d*128 + (((c*4+quad) ^ sw)*8));
        oacc[0][dt] = __builtin_amdgcn_mfma_f32_16x16x32_bf16(ap0, bv, oacc[0][dt], 0,0,0);
        oacc[1][dt] = __builtin_amdgcn_mfma_f32_16x16x32_bf16(ap1, bv, oacc[1][dt], 0,0,0);
      }
    }
  }
  #pragma unroll
  for(int g=0;g<2;g++){
    li[g] += __shfl_xor(li[g], 16);
    li[g] += __shfl_xor(li[g], 32);
  }
  #pragma unroll
  for(int g=0;g<2;g++){
    float linv[4];
    #pragma unroll
    for(int r=0;r<4;r++) linv[r] = 1.f / __shfl(li[g], quad*4+r);
    #pragma unroll
    for(int dt=0;dt<4;dt++){
      #pragma unroll
      for(int r=0;r<4;r++){
        const int row = q0 + g*16 + quad*4 + r;
        O[((size_t)(b*CN+row))*CE + h*CD + dt*16 + m16] = f2b(oacc[g][dt][r]*linv[r]);
      }
    }
  }
}

extern "C" void kernel_launch(void* const* d_in, const int* in_sizes, int n_in,
                              void* d_out, int out_size, void* d_ws, size_t ws_size,
                              hipStream_t stream)
{
  (void)in_sizes; (void)n_in; (void)out_size; (void)ws_size;
  const float* x     = (const float*)d_in[0];
  const float* w_qkv = (const float*)d_in[1];
  const float* b_qkv = (const float*)d_in[2];
  const float* w_proj= (const float*)d_in[3];
  const float* b_proj= (const float*)d_in[4];
  const float* g1    = (const float*)d_in[5];
  const float* be1   = (const float*)d_in[6];
  const float* g2    = (const float*)d_in[7];
  const float* be2   = (const float*)d_in[8];
  const float* w_fc1 = (const float*)d_in[9];
  const float* b_fc1 = (const float*)d_in[10];
  const float* w_fc2 = (const float*)d_in[11];
  const float* b_fc2 = (const float*)d_in[12];
  float* out = (float*)d_out;

  char* ws = (char*)d_ws;
  size_t off = 0;
  auto alloc = [&](size_t bytes)->char*{
    char* p = ws + off;
    off += (bytes + 255) & ~(size_t)255;
    return p;
  };
  bf16* wqkvT = (bf16*)alloc((size_t)3072*1024*2);  // [3E, E]
  bf16* wprojT= (bf16*)alloc((size_t)1024*1024*2);  // [E, E]
  bf16* wfc1T = (bf16*)alloc((size_t)4096*1024*2);  // [MLP, E]
  bf16* wfc2T = (bf16*)alloc((size_t)1024*4096*2);  // [E, MLP]
  bf16* h1    = (bf16*)alloc((size_t)CM*CE*2);      // LN out (reused for LN2)
  bf16* q     = (bf16*)alloc((size_t)CM*CE*2);      // [B,H,N,D]
  bf16* kk    = (bf16*)alloc((size_t)CM*CE*2);      // [B,H,N,D]
  bf16* vT    = (bf16*)alloc((size_t)CM*CE*2);      // [B,H,D,N]
  bf16* aO    = (bf16*)alloc((size_t)CM*CE*2);      // attn out [B,N,E]
  float* x2   = (float*)alloc((size_t)CM*CE*4);     // f32 trunk after proj
  bf16* hmlp  = q;  // reuse q..aO (4x8MB contiguous = 32MB) for bf16 [4096,4096]

  transpose_k<<<dim3(3072/32,1024/32),256,0,stream>>>(w_qkv, wqkvT, 1024,3072);
  transpose_k<<<dim3(1024/32,1024/32),256,0,stream>>>(w_proj, wprojT,1024,1024);
  transpose_k<<<dim3(4096/32,1024/32),256,0,stream>>>(w_fc1, wfc1T, 1024,4096);
  transpose_k<<<dim3(1024/32,4096/32),256,0,stream>>>(w_fc2, wfc2T, 4096,1024);

  ln_k<<<CM,256,0,stream>>>(x, g1, be1, h1);
  gemm256n_k<EP_QKV><<<dim3(16, 3072/128),512,0,stream>>>(
      h1, wqkvT, b_qkv, nullptr, q, kk, vT, 1024, 3072);
  attn_k<<<dim3(CN/128, CB*CH),256,0,stream>>>(q, kk, vT, aO);
  gemm64_k<<<dim3(16, 32),256,0,stream>>>(
      aO, wprojT, b_proj, x, x2, 1024, 1024);
  ln_k<<<CM,256,0,stream>>>(x2, g2, be2, h1);
  gemm256n_k<EP_GELU><<<dim3(16, 4096/128),512,0,stream>>>(
      h1, wfc1T, b_fc1, hmlp, nullptr, nullptr, nullptr, 1024, 4096);
  gemm64_k<<<dim3(16, 32),256,0,stream>>>(
      hmlp, wfc2T, b_fc2, x2, out, 4096, 1024);
}

// Round 5
// 343.219 us; speedup vs baseline: 1.1483x; 1.1483x over previous
//
#include <hip/hip_runtime.h>
#include <hip/hip_bf16.h>
#include <cmath>

// ---------------------------------------------------------------------------
// TransformerEncoderLayer, fp32 in/out (bf16 MFMA internally), MI355X gfx950.
// Pipeline: fused weight-transpose(f32->bf16T, ONE launch) -> LN1
//           -> GEMM(qkv,scatter) -> flash-attn -> GEMM(proj,+x -> f32 x2)
//           -> LN2 -> GEMM(fc1,GELU) -> GEMM(fc2,+x2 -> f32 out)
// v8 = R1 (best measured total, 351us) + two proven fixes:
//   - attn exp: guarded __builtin_amdgcn_exp2f (R2-proven fast; plain exp2f
//     = precise OCML path, cost +9us / VALUBusy 37->50 measured in R4).
//   - 4 transpose launches fused into 1 (launch-gap reduction).
// GEMM v3 (R1-proven): 128xBN tile, BK=64, 4 waves, mfma_f32_16x16x32_bf16;
//   global_load_lds w=16 with XOR-swizzled SOURCE (LDS slot s of row r holds
//   global chunk s^(r&7)) -> conflict-free ds_read_b128; XCD co-location
//   remap (same m-panel -> same lin%8); both BN paths double-buffered,
//   stage(k+1) issued BEFORE compute(k), ONE __syncthreads per iter.
//   Structural note (R2/R3/R4 falsified): bigger tiles, 8-phase raw-barrier
//   schedules, and 3-deep counted-vmcnt prefetch all REGRESSED vs this.
// Attention v2 (R1 core): 128-q-row blocks, K/V via gl_lds swizzled source;
//   no max-sub; deferred row-sum; XCD remap (FETCH 70->12MB measured).
// ---------------------------------------------------------------------------

typedef __hip_bfloat16 bf16;
typedef __bf16 bf16x8 __attribute__((ext_vector_type(8)));
typedef __bf16 bf16x4v __attribute__((ext_vector_type(4)));
typedef float  f32x4  __attribute__((ext_vector_type(4)));

#define CB 2
#define CN 2048
#define CE 1024
#define CH 16
#define CD 64
#define CMLP 4096
#define CM (CB*CN)   // 4096 tokens

#define PS 136       // attn P-tile LDS row stride (elems)

#define SM_SCALE_LOG2E 0.18033688011112042f   // 0.125 * log2(e)
#if __has_builtin(__builtin_amdgcn_exp2f)
#define FEXP(s) __builtin_amdgcn_exp2f((s)*SM_SCALE_LOG2E)
#else
#define FEXP(s) __expf((s)*0.125f)
#endif

__device__ __forceinline__ float b2f(bf16 v){ return __bfloat162float(v); }
__device__ __forceinline__ bf16  f2b(float v){ return __float2bfloat16(v); }

__device__ __forceinline__ void gl_lds16(const void* g, void* l){
  __builtin_amdgcn_global_load_lds((__attribute__((address_space(1))) void*)g,
                                   (__attribute__((address_space(3))) void*)l,
                                   16, 0, 0);
}

// Fused weight transpose: all 4 weights in ONE launch.
// in: f32 [K,N] row-major -> out: bf16 [N,K] row-major.
// tiles: qkv 96x32=3072, proj 32x32=1024, fc1 128x32=4096, fc2 32x128=4096.
__global__ __launch_bounds__(256) void transpose4_k(
  const float* __restrict__ i0, bf16* __restrict__ o0,
  const float* __restrict__ i1, bf16* __restrict__ o1,
  const float* __restrict__ i2, bf16* __restrict__ o2,
  const float* __restrict__ i3, bf16* __restrict__ o3)
{
  __shared__ float tile[32][33];
  int t = blockIdx.x;
  const float* in; bf16* out; int K, N, nx;
  if(t < 3072){            in=i0; out=o0; K=1024; N=3072; nx=96; }
  else if(t < 4096){ t-=3072; in=i1; out=o1; K=1024; N=1024; nx=32; }
  else if(t < 8192){ t-=4096; in=i2; out=o2; K=1024; N=4096; nx=128; }
  else {             t-=8192; in=i3; out=o3; K=4096; N=1024; nx=32; }
  const int n0 = (t%nx)*32, k0 = (t/nx)*32;
  const int tx = threadIdx.x & 31;
  const int ty = threadIdx.x >> 5;   // 0..7
  #pragma unroll
  for(int i=0;i<32;i+=8) tile[ty+i][tx] = in[(size_t)(k0+ty+i)*N + n0+tx];
  __syncthreads();
  #pragma unroll
  for(int i=0;i<32;i+=8) out[(size_t)(n0+ty+i)*K + k0+tx] = f2b(tile[tx][ty+i]);
}

// LayerNorm: one row (E=1024) per 256-thread block; f32 in -> bf16 out
__global__ __launch_bounds__(256) void ln_k(const float* __restrict__ x,
                                            const float* __restrict__ g,
                                            const float* __restrict__ be,
                                            bf16* __restrict__ out){
  const int row = blockIdx.x;
  const int t = threadIdx.x;
  const float4 v4 = ((const float4*)(x + (size_t)row*CE))[t];
  float v[4] = {v4.x, v4.y, v4.z, v4.w};
  float s=0.f, s2=0.f;
  #pragma unroll
  for(int i=0;i<4;i++){ s+=v[i]; s2+=v[i]*v[i]; }
  #pragma unroll
  for(int off=32; off>0; off>>=1){ s += __shfl_down(s,off); s2 += __shfl_down(s2,off); }
  __shared__ float red[8];
  __shared__ float mu_s, rs_s;
  const int wv=t>>6, ln=t&63;
  if(ln==0){ red[wv]=s; red[4+wv]=s2; }
  __syncthreads();
  if(t==0){
    float S=red[0]+red[1]+red[2]+red[3], S2=red[4]+red[5]+red[6]+red[7];
    float mu=S/CE;
    mu_s=mu; rs_s=rsqrtf(S2/CE - mu*mu + 1e-5f);
  }
  __syncthreads();
  const float mu=mu_s, rs=rs_s;
  #pragma unroll
  for(int i=0;i<4;i++){
    int c=t*4+i;
    out[(size_t)row*CE+c] = f2b((v[i]-mu)*rs*g[c] + be[c]);
  }
}

#define EP_QKV 0
#define EP_RES 1
#define EP_GELU 2

// C = A[M,K](bf16) * BT[N,K](bf16)^T (+f32 bias; epilogue per MODE)
// Tile 128 x BN, BK=64; 4 waves, each 64 x BN/2 (MI=4, NJ=BN/32).
// Requires gridDim.y == 32 (M=4096) for the XCD remap.
template<int MODE, int BN>
__global__ __launch_bounds__(256,2) void gemm_k(
  const bf16* __restrict__ A, const bf16* __restrict__ BT,
  const float* __restrict__ bias, const float* __restrict__ res,
  float* __restrict__ Cf, bf16* __restrict__ Cb,
  bf16* __restrict__ Cq, bf16* __restrict__ Ck, bf16* __restrict__ Cv,
  int Ksz, int Nsz)
{
  constexpr int NJ = BN/32;           // B frags per wave (2 or 4)
  __shared__ __align__(16) bf16 Alds[2][128*64];
  __shared__ __align__(16) bf16 Blds[2][BN*64];
  const int tid = threadIdx.x;
  const int wave = tid>>6, lane = tid&63;
  const int m16 = lane&15, quad = lane>>4;
  const int wi = wave>>1, wj = wave&1;

  // XCD co-location: same m-tile -> same lin%8 -> same XCD L2 holds A-tile.
  const int lin = blockIdx.x + gridDim.x*blockIdx.y;
  const int m_idx = (lin&7) + 8*((lin>>3)&3);
  const int n_idx = lin>>5;
  const size_t m0 = (size_t)m_idx*128;
  const size_t n0 = (size_t)n_idx*BN;

  f32x4 acc[4][NJ] = {};

  // staging: instr j covers 8 rows; lane -> row +lane/8, swizzled chunk
  const int srow8 = lane>>3;                   // 0..7
  const int schk  = ((lane&7)^srow8)*8;        // elem offset, XOR swizzle
  const bf16* pA = A  + (m0 + 32*wave      + srow8)*(size_t)Ksz + schk;
  const bf16* pB = BT + (n0 + (BN/4)*wave  + srow8)*(size_t)Ksz + schk;

  auto stage = [&](int buf, const bf16* gA, const bf16* gB){
    bf16* lA = &Alds[buf][wave*2048];          // 32 rows * 64 elems
    bf16* lB = &Blds[buf][wave*(BN*16)];       // BN/4 rows * 64 elems
    #pragma unroll
    for(int j=0;j<4;j++)  gl_lds16(gA + (size_t)(j*8)*Ksz, lA + j*512);
    #pragma unroll
    for(int j=0;j<NJ;j++) gl_lds16(gB + (size_t)(j*8)*Ksz, lB + j*512);
  };
  auto compute = [&](int buf){
    #pragma unroll
    for(int w=0;w<2;w++){
      const int sw = (m16&7);
      bf16x8 af[4], bfr[NJ];
      #pragma unroll
      for(int i=0;i<4;i++){
        const int row = wi*64+16*i+m16;
        af[i] = *(const bf16x8*)(&Alds[buf][row*64 + ((w*4+quad)^sw)*8]);
      }
      #pragma unroll
      for(int j=0;j<NJ;j++){
        const int row = wj*(BN/2)+16*j+m16;
        bfr[j] = *(const bf16x8*)(&Blds[buf][row*64 + ((w*4+quad)^sw)*8]);
      }
      #pragma unroll
      for(int i=0;i<4;i++)
        #pragma unroll
        for(int j=0;j<NJ;j++)
          acc[i][j] = __builtin_amdgcn_mfma_f32_16x16x32_bf16(af[i], bfr[j], acc[i][j], 0,0,0);
    }
  };

  // Double-buffered main loop, ONE barrier/iter: the barrier's implicit
  // vmcnt(0) drain waits for tile kb (issued an iteration earlier, its
  // latency hidden under compute(kb-1)); stage(kb+1) is issued before
  // compute(kb) so it has the whole compute phase to land.
  const int kIters = Ksz/64;
  stage(0, pA, pB); pA += 64; pB += 64;
  for(int kb=0; kb<kIters; ++kb){
    __syncthreads();                  // tile kb landed; compute(kb-1) done
    if(kb+1<kIters){ stage((kb+1)&1, pA, pB); pA += 64; pB += 64; }
    compute(kb&1);                    // overlaps tile kb+1 load latency
  }

  // epilogue: elem (row = m0+wi*64+16i+quad*4+r, col = n0+wj*(BN/2)+16j+m16)
  #pragma unroll
  for(int i=0;i<4;i++){
    #pragma unroll
    for(int j=0;j<NJ;j++){
      const int col = (int)n0 + wj*(BN/2) + 16*j + m16;
      const float bcol = bias[col];
      #pragma unroll
      for(int r=0;r<4;r++){
        const int row = (int)m0 + wi*64 + 16*i + quad*4 + r;
        float v = acc[i][j][r] + bcol;
        if constexpr (MODE==EP_QKV){
          const int b = row>>11, n = row&2047;
          const int which = col>>10, cc = col&1023;
          const int h = cc>>6, d = cc&63;
          if(which==0)      Cq[(((size_t)(b*CH+h))*CN+n)*CD + d] = f2b(v);
          else if(which==1) Ck[(((size_t)(b*CH+h))*CN+n)*CD + d] = f2b(v);
          else              Cv[(((size_t)(b*CH+h))*CD+d)*CN + n] = f2b(v);
        } else if constexpr (MODE==EP_RES){
          v += res[(size_t)row*Nsz+col];
          Cf[(size_t)row*Nsz+col] = v;
        } else { // EP_GELU: tanh-form, branch-free.
          const float u2 = 1.5957691216f*(v + 0.044715f*v*v*v);
          v = v * (1.f/(1.f + __expf(-u2)));
          Cb[(size_t)row*Nsz+col] = f2b(v);
        }
      }
    }
  }
}

// Flash attention: grid (16,32) remapped so all 16 q-blocks of one (b,h)
// share lin%8 (same XCD -> K/V re-reads hit that XCD's L2; FETCH 70->12MB).
// 4 waves; wave = 32 q-rows (2 groups of 16); key tiles of 128 in LDS.
// S^T = K*Q^T (packed b64 P-stores); no max-sub; deferred row-sum.
// Q,K: bf16 [B,H,N,D]; Vt: bf16 [B,H,D,N]; O: bf16 [B,N,E] (col = h*64+d)
__global__ __launch_bounds__(256,2) void attn_k(
  const bf16* __restrict__ Q, const bf16* __restrict__ Kx,
  const bf16* __restrict__ Vt, bf16* __restrict__ O)
{
  const int lin = blockIdx.x + gridDim.x*blockIdx.y;
  const int bh = (lin&7) + 8*(lin>>7);
  const int qblk = (lin>>3)&15;
  const int b = bh>>4, h = bh&15;
  const int tid = threadIdx.x;
  const int wave = tid>>6, lane = tid&63;
  const int m16 = lane&15, quad = lane>>4;
  const int sw = m16&7;
  const int q0 = qblk*128 + wave*32;

  const bf16* Qb = Q  + (size_t)bh*CN*CD;
  const bf16* Kb = Kx + (size_t)bh*CN*CD;
  const bf16* Vb = Vt + (size_t)bh*CD*CN;

  bf16x8 qf[2][2];
  #pragma unroll
  for(int g=0;g<2;g++){
    const bf16* qp = Qb + (size_t)(q0+g*16+m16)*CD + quad*8;
    qf[g][0] = *(const bf16x8*)(qp);
    qf[g][1] = *(const bf16x8*)(qp + 32);
  }

  float li[2] = {0.f, 0.f};
  f32x4 oacc[2][4] = {};

  __shared__ __align__(16) bf16 Klds[128*64];   // 16 KB
  __shared__ __align__(16) bf16 Vlds[64*128];   // 16 KB
  __shared__ __align__(16) bf16 Plds[4][32*PS]; // 34.8 KB
  bf16* Pw = &Plds[wave][0];

  const int krow = wave*32 + (lane>>3);
  const int kchk = (lane&7) ^ (lane>>3);
  const bf16* pK = Kb + (size_t)krow*CD + kchk*8;
  const int vrow = wave*16 + (lane>>4);
  const bf16* pV[4];
  #pragma unroll
  for(int j=0;j<4;j++){
    const int ck = (lane&15) ^ ((j*4 + (lane>>4)) & 7);
    pV[j] = Vb + (size_t)(vrow + j*4)*CN + ck*8;
  }
  bf16* lK = Klds + wave*2048;
  bf16* lV = Vlds + wave*2048;

  for(int kt=0; kt<CN; kt+=128){
    __syncthreads();
    #pragma unroll
    for(int j=0;j<4;j++){
      gl_lds16(pK + (size_t)j*8*CD, lK + j*512);
      gl_lds16(pV[j],               lV + j*512);
      pV[j] += 128;
    }
    pK += (size_t)128*CD;
    __syncthreads();

    f32x4 sf0[8], sf1[8];
    #pragma unroll
    for(int f=0;f<8;f++){
      const bf16* kb = Klds + (f*16+m16)*64;
      bf16x8 k0 = *(const bf16x8*)(kb + ((quad   ^ sw)*8));
      bf16x8 k1 = *(const bf16x8*)(kb + (((quad+4)^ sw)*8));
      f32x4 t0 = {}, t1 = {};
      t0 = __builtin_amdgcn_mfma_f32_16x16x32_bf16(k0, qf[0][0], t0, 0,0,0);
      t0 = __builtin_amdgcn_mfma_f32_16x16x32_bf16(k1, qf[0][1], t0, 0,0,0);
      t1 = __builtin_amdgcn_mfma_f32_16x16x32_bf16(k0, qf[1][0], t1, 0,0,0);
      t1 = __builtin_amdgcn_mfma_f32_16x16x32_bf16(k1, qf[1][1], t1, 0,0,0);
      sf0[f]=t0; sf1[f]=t1;
    }
    #pragma unroll
    for(int f=0;f<8;f++){
      bf16x4v p0, p1;
      #pragma unroll
      for(int r=0;r<4;r++){
        float e0 = FEXP(sf0[f][r]); li[0]+=e0; p0[r]=(__bf16)e0;
        float e1 = FEXP(sf1[f][r]); li[1]+=e1; p1[r]=(__bf16)e1;
      }
      *(bf16x4v*)(Pw + (size_t)m16*PS       + f*16 + quad*4) = p0;
      *(bf16x4v*)(Pw + (size_t)(16+m16)*PS  + f*16 + quad*4) = p1;
    }
    asm volatile("s_waitcnt lgkmcnt(0)" ::: "memory");
    #pragma unroll
    for(int c=0;c<4;c++){
      const bf16x8 ap0 = *(const bf16x8*)(Pw + (size_t)m16*PS      + c*32 + quad*8);
      const bf16x8 ap1 = *(const bf16x8*)(Pw + (size_t)(16+m16)*PS + c*32 + quad*8);
      #pragma unroll
      for(int dt=0;dt<4;dt++){
        const int d = dt*16+m16;
        bf16x8 bv = *(const bf16x8*)(Vlds + d*128 + (((c*4+quad) ^ sw)*8));
        oacc[0][dt] = __builtin_amdgcn_mfma_f32_16x16x32_bf16(ap0, bv, oacc[0][dt], 0,0,0);
        oacc[1][dt] = __builtin_amdgcn_mfma_f32_16x16x32_bf16(ap1, bv, oacc[1][dt], 0,0,0);
      }
    }
  }
  #pragma unroll
  for(int g=0;g<2;g++){
    li[g] += __shfl_xor(li[g], 16);
    li[g] += __shfl_xor(li[g], 32);
  }
  #pragma unroll
  for(int g=0;g<2;g++){
    float linv[4];
    #pragma unroll
    for(int r=0;r<4;r++) linv[r] = 1.f / __shfl(li[g], quad*4+r);
    #pragma unroll
    for(int dt=0;dt<4;dt++){
      #pragma unroll
      for(int r=0;r<4;r++){
        const int row = q0 + g*16 + quad*4 + r;
        O[((size_t)(b*CN+row))*CE + h*CD + dt*16 + m16] = f2b(oacc[g][dt][r]*linv[r]);
      }
    }
  }
}

extern "C" void kernel_launch(void* const* d_in, const int* in_sizes, int n_in,
                              void* d_out, int out_size, void* d_ws, size_t ws_size,
                              hipStream_t stream)
{
  (void)in_sizes; (void)n_in; (void)out_size; (void)ws_size;
  const float* x     = (const float*)d_in[0];
  const float* w_qkv = (const float*)d_in[1];
  const float* b_qkv = (const float*)d_in[2];
  const float* w_proj= (const float*)d_in[3];
  const float* b_proj= (const float*)d_in[4];
  const float* g1    = (const float*)d_in[5];
  const float* be1   = (const float*)d_in[6];
  const float* g2    = (const float*)d_in[7];
  const float* be2   = (const float*)d_in[8];
  const float* w_fc1 = (const float*)d_in[9];
  const float* b_fc1 = (const float*)d_in[10];
  const float* w_fc2 = (const float*)d_in[11];
  const float* b_fc2 = (const float*)d_in[12];
  float* out = (float*)d_out;

  char* ws = (char*)d_ws;
  size_t off = 0;
  auto alloc = [&](size_t bytes)->char*{
    char* p = ws + off;
    off += (bytes + 255) & ~(size_t)255;
    return p;
  };
  bf16* wqkvT = (bf16*)alloc((size_t)3072*1024*2);  // [3E, E]
  bf16* wprojT= (bf16*)alloc((size_t)1024*1024*2);  // [E, E]
  bf16* wfc1T = (bf16*)alloc((size_t)4096*1024*2);  // [MLP, E]
  bf16* wfc2T = (bf16*)alloc((size_t)1024*4096*2);  // [E, MLP]
  bf16* h1    = (bf16*)alloc((size_t)CM*CE*2);      // LN out (reused for LN2)
  bf16* q     = (bf16*)alloc((size_t)CM*CE*2);      // [B,H,N,D]
  bf16* kk    = (bf16*)alloc((size_t)CM*CE*2);      // [B,H,N,D]
  bf16* vT    = (bf16*)alloc((size_t)CM*CE*2);      // [B,H,D,N]
  bf16* aO    = (bf16*)alloc((size_t)CM*CE*2);      // attn out [B,N,E]
  float* x2   = (float*)alloc((size_t)CM*CE*4);     // f32 trunk after proj
  bf16* hmlp  = q;  // reuse q..aO (4x8MB contiguous = 32MB) for bf16 [4096,4096]

  transpose4_k<<<12288,256,0,stream>>>(w_qkv, wqkvT, w_proj, wprojT,
                                       w_fc1, wfc1T, w_fc2, wfc2T);

  ln_k<<<CM,256,0,stream>>>(x, g1, be1, h1);
  gemm_k<EP_QKV,128><<<dim3(3072/128, CM/128),256,0,stream>>>(
      h1, wqkvT, b_qkv, nullptr, nullptr, nullptr, q, kk, vT, 1024, 3072);
  attn_k<<<dim3(CN/128, CB*CH),256,0,stream>>>(q, kk, vT, aO);
  gemm_k<EP_RES,64><<<dim3(1024/64, CM/128),256,0,stream>>>(
      aO, wprojT, b_proj, x, x2, nullptr, nullptr,nullptr,nullptr, 1024, 1024);
  ln_k<<<CM,256,0,stream>>>(x2, g2, be2, h1);
  gemm_k<EP_GELU,128><<<dim3(4096/128, CM/128),256,0,stream>>>(
      h1, wfc1T, b_fc1, nullptr, nullptr, hmlp, nullptr,nullptr,nullptr, 1024, 4096);
  gemm_k<EP_RES,64><<<dim3(1024/64, CM/128),256,0,stream>>>(
      hmlp, wfc2T, b_fc2, x2, out, nullptr, nullptr,nullptr,nullptr, 4096, 1024);
}

// Round 6
// 339.015 us; speedup vs baseline: 1.1625x; 1.0124x over previous
//
#include <hip/hip_runtime.h>
#include <hip/hip_bf16.h>
#include <cmath>

// ---------------------------------------------------------------------------
// TransformerEncoderLayer, fp32 in/out (bf16 MFMA internally), MI355X gfx950.
// Pipeline: fused weight-transpose(f32->bf16T, ONE launch) -> LN1
//           -> GEMM(qkv,scatter) -> flash-attn -> GEMM(proj,+x -> f32 x2)
//           -> LN2 -> GEMM(fc1,GELU) -> GEMM(fc2,+x2 -> f32 out)
// v9 = R5 (proven 343us) + ONE isolated change:
//   BN=64 GEMM path (proj/fc2): NBUF=3, 2-tile-ahead prefetch, counted
//   s_waitcnt vmcnt(6) + raw s_barrier (one per iter). R5 counters showed
//   fc2 at 60.5us = 2270cy/iter vs ~1150cy LDS/MFMA floor -> half the time
//   is un-hidden global latency at 2 blk/CU with 1-iter lookahead.
//   Hazards: wait-point iter kb has tiles {kb,kb+1} outstanding -> vmcnt(6)
//   forces own tile-kb (6 loads), barrier publishes all waves'; tail iter
//   drains vmcnt(0); stage(kb+2) overwrites buf (kb+2)%3 whose last readers
//   completed before the just-crossed barrier. LDS 72KB -> still 2 blk/CU.
// GEMM v3 (R1/R5-proven) otherwise: 128xBN tile, BK=64, 4 waves;
//   global_load_lds w=16 with XOR-swizzled SOURCE (LDS slot s of row r holds
//   global chunk s^(r&7)) -> conflict-free ds_read_b128; XCD co-location
//   remap (same m-panel -> same lin%8); BN=128 path keeps the 2-buffer
//   __syncthreads loop (R2/R3/R4 falsified bigger tiles / 8-phase / deep
//   prefetch at 8-wave geometry).
// Attention (R5-proven 63us): XCD remap, guarded __builtin_amdgcn_exp2f.
// ---------------------------------------------------------------------------

typedef __hip_bfloat16 bf16;
typedef __bf16 bf16x8 __attribute__((ext_vector_type(8)));
typedef __bf16 bf16x4v __attribute__((ext_vector_type(4)));
typedef float  f32x4  __attribute__((ext_vector_type(4)));

#define CB 2
#define CN 2048
#define CE 1024
#define CH 16
#define CD 64
#define CMLP 4096
#define CM (CB*CN)   // 4096 tokens

#define PS 136       // attn P-tile LDS row stride (elems)

#define SM_SCALE_LOG2E 0.18033688011112042f   // 0.125 * log2(e)
#if __has_builtin(__builtin_amdgcn_exp2f)
#define FEXP(s) __builtin_amdgcn_exp2f((s)*SM_SCALE_LOG2E)
#else
#define FEXP(s) __expf((s)*0.125f)
#endif

__device__ __forceinline__ float b2f(bf16 v){ return __bfloat162float(v); }
__device__ __forceinline__ bf16  f2b(float v){ return __float2bfloat16(v); }

__device__ __forceinline__ void gl_lds16(const void* g, void* l){
  __builtin_amdgcn_global_load_lds((__attribute__((address_space(1))) void*)g,
                                   (__attribute__((address_space(3))) void*)l,
                                   16, 0, 0);
}

#define FENCE asm volatile("" ::: "memory")
#define BAR   do{ FENCE; __builtin_amdgcn_s_barrier(); FENCE; }while(0)
#define VMW6  asm volatile("s_waitcnt vmcnt(6)" ::: "memory")
#define VMW0  asm volatile("s_waitcnt vmcnt(0)" ::: "memory")

// Fused weight transpose: all 4 weights in ONE launch.
// in: f32 [K,N] row-major -> out: bf16 [N,K] row-major.
// tiles: qkv 96x32=3072, proj 32x32=1024, fc1 128x32=4096, fc2 32x128=4096.
__global__ __launch_bounds__(256) void transpose4_k(
  const float* __restrict__ i0, bf16* __restrict__ o0,
  const float* __restrict__ i1, bf16* __restrict__ o1,
  const float* __restrict__ i2, bf16* __restrict__ o2,
  const float* __restrict__ i3, bf16* __restrict__ o3)
{
  __shared__ float tile[32][33];
  int t = blockIdx.x;
  const float* in; bf16* out; int K, N, nx;
  if(t < 3072){            in=i0; out=o0; K=1024; N=3072; nx=96; }
  else if(t < 4096){ t-=3072; in=i1; out=o1; K=1024; N=1024; nx=32; }
  else if(t < 8192){ t-=4096; in=i2; out=o2; K=1024; N=4096; nx=128; }
  else {             t-=8192; in=i3; out=o3; K=4096; N=1024; nx=32; }
  const int n0 = (t%nx)*32, k0 = (t/nx)*32;
  const int tx = threadIdx.x & 31;
  const int ty = threadIdx.x >> 5;   // 0..7
  #pragma unroll
  for(int i=0;i<32;i+=8) tile[ty+i][tx] = in[(size_t)(k0+ty+i)*N + n0+tx];
  __syncthreads();
  #pragma unroll
  for(int i=0;i<32;i+=8) out[(size_t)(n0+ty+i)*K + k0+tx] = f2b(tile[tx][ty+i]);
}

// LayerNorm: one row (E=1024) per 256-thread block; f32 in -> bf16 out
__global__ __launch_bounds__(256) void ln_k(const float* __restrict__ x,
                                            const float* __restrict__ g,
                                            const float* __restrict__ be,
                                            bf16* __restrict__ out){
  const int row = blockIdx.x;
  const int t = threadIdx.x;
  const float4 v4 = ((const float4*)(x + (size_t)row*CE))[t];
  float v[4] = {v4.x, v4.y, v4.z, v4.w};
  float s=0.f, s2=0.f;
  #pragma unroll
  for(int i=0;i<4;i++){ s+=v[i]; s2+=v[i]*v[i]; }
  #pragma unroll
  for(int off=32; off>0; off>>=1){ s += __shfl_down(s,off); s2 += __shfl_down(s2,off); }
  __shared__ float red[8];
  __shared__ float mu_s, rs_s;
  const int wv=t>>6, ln=t&63;
  if(ln==0){ red[wv]=s; red[4+wv]=s2; }
  __syncthreads();
  if(t==0){
    float S=red[0]+red[1]+red[2]+red[3], S2=red[4]+red[5]+red[6]+red[7];
    float mu=S/CE;
    mu_s=mu; rs_s=rsqrtf(S2/CE - mu*mu + 1e-5f);
  }
  __syncthreads();
  const float mu=mu_s, rs=rs_s;
  #pragma unroll
  for(int i=0;i<4;i++){
    int c=t*4+i;
    out[(size_t)row*CE+c] = f2b((v[i]-mu)*rs*g[c] + be[c]);
  }
}

#define EP_QKV 0
#define EP_RES 1
#define EP_GELU 2

// C = A[M,K](bf16) * BT[N,K](bf16)^T (+f32 bias; epilogue per MODE)
// Tile 128 x BN, BK=64; 4 waves, each 64 x BN/2 (MI=4, NJ=BN/32).
// Requires gridDim.y == 32 (M=4096) for the XCD remap.
template<int MODE, int BN>
__global__ __launch_bounds__(256,2) void gemm_k(
  const bf16* __restrict__ A, const bf16* __restrict__ BT,
  const float* __restrict__ bias, const float* __restrict__ res,
  float* __restrict__ Cf, bf16* __restrict__ Cb,
  bf16* __restrict__ Cq, bf16* __restrict__ Ck, bf16* __restrict__ Cv,
  int Ksz, int Nsz)
{
  constexpr int NJ = BN/32;           // B frags per wave (2 or 4)
  constexpr int NBUF = (BN==64) ? 3 : 2;
  __shared__ __align__(16) bf16 Alds[NBUF][128*64];
  __shared__ __align__(16) bf16 Blds[NBUF][BN*64];
  const int tid = threadIdx.x;
  const int wave = tid>>6, lane = tid&63;
  const int m16 = lane&15, quad = lane>>4;
  const int wi = wave>>1, wj = wave&1;

  // XCD co-location: same m-tile -> same lin%8 -> same XCD L2 holds A-tile.
  const int lin = blockIdx.x + gridDim.x*blockIdx.y;
  const int m_idx = (lin&7) + 8*((lin>>3)&3);
  const int n_idx = lin>>5;
  const size_t m0 = (size_t)m_idx*128;
  const size_t n0 = (size_t)n_idx*BN;

  f32x4 acc[4][NJ] = {};

  // staging: instr j covers 8 rows; lane -> row +lane/8, swizzled chunk
  const int srow8 = lane>>3;                   // 0..7
  const int schk  = ((lane&7)^srow8)*8;        // elem offset, XOR swizzle
  const bf16* pA = A  + (m0 + 32*wave      + srow8)*(size_t)Ksz + schk;
  const bf16* pB = BT + (n0 + (BN/4)*wave  + srow8)*(size_t)Ksz + schk;

  auto stage = [&](int buf, const bf16* gA, const bf16* gB){
    bf16* lA = &Alds[buf][wave*2048];          // 32 rows * 64 elems
    bf16* lB = &Blds[buf][wave*(BN*16)];       // BN/4 rows * 64 elems
    #pragma unroll
    for(int j=0;j<4;j++)  gl_lds16(gA + (size_t)(j*8)*Ksz, lA + j*512);
    #pragma unroll
    for(int j=0;j<NJ;j++) gl_lds16(gB + (size_t)(j*8)*Ksz, lB + j*512);
  };
  auto compute = [&](int buf){
    #pragma unroll
    for(int w=0;w<2;w++){
      const int sw = (m16&7);
      bf16x8 af[4], bfr[NJ];
      #pragma unroll
      for(int i=0;i<4;i++){
        const int row = wi*64+16*i+m16;
        af[i] = *(const bf16x8*)(&Alds[buf][row*64 + ((w*4+quad)^sw)*8]);
      }
      #pragma unroll
      for(int j=0;j<NJ;j++){
        const int row = wj*(BN/2)+16*j+m16;
        bfr[j] = *(const bf16x8*)(&Blds[buf][row*64 + ((w*4+quad)^sw)*8]);
      }
      #pragma unroll
      for(int i=0;i<4;i++)
        #pragma unroll
        for(int j=0;j<NJ;j++)
          acc[i][j] = __builtin_amdgcn_mfma_f32_16x16x32_bf16(af[i], bfr[j], acc[i][j], 0,0,0);
    }
  };

  const int kIters = Ksz/64;
  if constexpr (BN==64){
    // 3-buffer, 2-tile-ahead prefetch; counted vmcnt + raw barrier per iter.
    stage(0, pA, pB); pA += 64; pB += 64;
    stage(1, pA, pB); pA += 64; pB += 64;
    int bc = 0, bs = 2;
    for(int kb=0; kb<kIters; ++kb){
      if(kb==kIters-1){ VMW0; } else { VMW6; }   // own tile-kb loads landed
      BAR;                                        // -> all waves' tile kb
      if(kb+2<kIters){ stage(bs, pA, pB); pA += 64; pB += 64; }
      compute(bc);
      bc = (bc==2)?0:bc+1;
      bs = (bs==2)?0:bs+1;
    }
  } else {
    // Proven 2-buffer loop: ONE __syncthreads per iter (implicit vmcnt(0)
    // drain waits tile kb issued a full compute phase earlier).
    stage(0, pA, pB); pA += 64; pB += 64;
    for(int kb=0; kb<kIters; ++kb){
      __syncthreads();                  // tile kb landed; compute(kb-1) done
      if(kb+1<kIters){ stage((kb+1)&1, pA, pB); pA += 64; pB += 64; }
      compute(kb&1);                    // overlaps tile kb+1 load latency
    }
  }

  // epilogue: elem (row = m0+wi*64+16i+quad*4+r, col = n0+wj*(BN/2)+16j+m16)
  #pragma unroll
  for(int i=0;i<4;i++){
    #pragma unroll
    for(int j=0;j<NJ;j++){
      const int col = (int)n0 + wj*(BN/2) + 16*j + m16;
      const float bcol = bias[col];
      #pragma unroll
      for(int r=0;r<4;r++){
        const int row = (int)m0 + wi*64 + 16*i + quad*4 + r;
        float v = acc[i][j][r] + bcol;
        if constexpr (MODE==EP_QKV){
          const int b = row>>11, n = row&2047;
          const int which = col>>10, cc = col&1023;
          const int h = cc>>6, d = cc&63;
          if(which==0)      Cq[(((size_t)(b*CH+h))*CN+n)*CD + d] = f2b(v);
          else if(which==1) Ck[(((size_t)(b*CH+h))*CN+n)*CD + d] = f2b(v);
          else              Cv[(((size_t)(b*CH+h))*CD+d)*CN + n] = f2b(v);
        } else if constexpr (MODE==EP_RES){
          v += res[(size_t)row*Nsz+col];
          Cf[(size_t)row*Nsz+col] = v;
        } else { // EP_GELU: tanh-form, branch-free.
          const float u2 = 1.5957691216f*(v + 0.044715f*v*v*v);
          v = v * (1.f/(1.f + __expf(-u2)));
          Cb[(size_t)row*Nsz+col] = f2b(v);
        }
      }
    }
  }
}

// Flash attention: grid (16,32) remapped so all 16 q-blocks of one (b,h)
// share lin%8 (same XCD -> K/V re-reads hit that XCD's L2; FETCH 70->12MB).
// 4 waves; wave = 32 q-rows (2 groups of 16); key tiles of 128 in LDS.
// S^T = K*Q^T (packed b64 P-stores); no max-sub; deferred row-sum.
// Q,K: bf16 [B,H,N,D]; Vt: bf16 [B,H,D,N]; O: bf16 [B,N,E] (col = h*64+d)
__global__ __launch_bounds__(256,2) void attn_k(
  const bf16* __restrict__ Q, const bf16* __restrict__ Kx,
  const bf16* __restrict__ Vt, bf16* __restrict__ O)
{
  const int lin = blockIdx.x + gridDim.x*blockIdx.y;
  const int bh = (lin&7) + 8*(lin>>7);
  const int qblk = (lin>>3)&15;
  const int b = bh>>4, h = bh&15;
  const int tid = threadIdx.x;
  const int wave = tid>>6, lane = tid&63;
  const int m16 = lane&15, quad = lane>>4;
  const int sw = m16&7;
  const int q0 = qblk*128 + wave*32;

  const bf16* Qb = Q  + (size_t)bh*CN*CD;
  const bf16* Kb = Kx + (size_t)bh*CN*CD;
  const bf16* Vb = Vt + (size_t)bh*CD*CN;

  bf16x8 qf[2][2];
  #pragma unroll
  for(int g=0;g<2;g++){
    const bf16* qp = Qb + (size_t)(q0+g*16+m16)*CD + quad*8;
    qf[g][0] = *(const bf16x8*)(qp);
    qf[g][1] = *(const bf16x8*)(qp + 32);
  }

  float li[2] = {0.f, 0.f};
  f32x4 oacc[2][4] = {};

  __shared__ __align__(16) bf16 Klds[128*64];   // 16 KB
  __shared__ __align__(16) bf16 Vlds[64*128];   // 16 KB
  __shared__ __align__(16) bf16 Plds[4][32*PS]; // 34.8 KB
  bf16* Pw = &Plds[wave][0];

  const int krow = wave*32 + (lane>>3);
  const int kchk = (lane&7) ^ (lane>>3);
  const bf16* pK = Kb + (size_t)krow*CD + kchk*8;
  const int vrow = wave*16 + (lane>>4);
  const bf16* pV[4];
  #pragma unroll
  for(int j=0;j<4;j++){
    const int ck = (lane&15) ^ ((j*4 + (lane>>4)) & 7);
    pV[j] = Vb + (size_t)(vrow + j*4)*CN + ck*8;
  }
  bf16* lK = Klds + wave*2048;
  bf16* lV = Vlds + wave*2048;

  for(int kt=0; kt<CN; kt+=128){
    __syncthreads();
    #pragma unroll
    for(int j=0;j<4;j++){
      gl_lds16(pK + (size_t)j*8*CD, lK + j*512);
      gl_lds16(pV[j],               lV + j*512);
      pV[j] += 128;
    }
    pK += (size_t)128*CD;
    __syncthreads();

    f32x4 sf0[8], sf1[8];
    #pragma unroll
    for(int f=0;f<8;f++){
      const bf16* kb = Klds + (f*16+m16)*64;
      bf16x8 k0 = *(const bf16x8*)(kb + ((quad   ^ sw)*8));
      bf16x8 k1 = *(const bf16x8*)(kb + (((quad+4)^ sw)*8));
      f32x4 t0 = {}, t1 = {};
      t0 = __builtin_amdgcn_mfma_f32_16x16x32_bf16(k0, qf[0][0], t0, 0,0,0);
      t0 = __builtin_amdgcn_mfma_f32_16x16x32_bf16(k1, qf[0][1], t0, 0,0,0);
      t1 = __builtin_amdgcn_mfma_f32_16x16x32_bf16(k0, qf[1][0], t1, 0,0,0);
      t1 = __builtin_amdgcn_mfma_f32_16x16x32_bf16(k1, qf[1][1], t1, 0,0,0);
      sf0[f]=t0; sf1[f]=t1;
    }
    #pragma unroll
    for(int f=0;f<8;f++){
      bf16x4v p0, p1;
      #pragma unroll
      for(int r=0;r<4;r++){
        float e0 = FEXP(sf0[f][r]); li[0]+=e0; p0[r]=(__bf16)e0;
        float e1 = FEXP(sf1[f][r]); li[1]+=e1; p1[r]=(__bf16)e1;
      }
      *(bf16x4v*)(Pw + (size_t)m16*PS       + f*16 + quad*4) = p0;
      *(bf16x4v*)(Pw + (size_t)(16+m16)*PS  + f*16 + quad*4) = p1;
    }
    asm volatile("s_waitcnt lgkmcnt(0)" ::: "memory");
    #pragma unroll
    for(int c=0;c<4;c++){
      const bf16x8 ap0 = *(const bf16x8*)(Pw + (size_t)m16*PS      + c*32 + quad*8);
      const bf16x8 ap1 = *(const bf16x8*)(Pw + (size_t)(16+m16)*PS + c*32 + quad*8);
      #pragma unroll
      for(int dt=0;dt<4;dt++){
        const int d = dt*16+m16;
        bf16x8 bv = *(const bf16x8*)(Vlds + d*128 + (((c*4+quad) ^ sw)*8));
        oacc[0][dt] = __builtin_amdgcn_mfma_f32_16x16x32_bf16(ap0, bv, oacc[0][dt], 0,0,0);
        oacc[1][dt] = __builtin_amdgcn_mfma_f32_16x16x32_bf16(ap1, bv, oacc[1][dt], 0,0,0);
      }
    }
  }
  #pragma unroll
  for(int g=0;g<2;g++){
    li[g] += __shfl_xor(li[g], 16);
    li[g] += __shfl_xor(li[g], 32);
  }
  #pragma unroll
  for(int g=0;g<2;g++){
    float linv[4];
    #pragma unroll
    for(int r=0;r<4;r++) linv[r] = 1.f / __shfl(li[g], quad*4+r);
    #pragma unroll
    for(int dt=0;dt<4;dt++){
      #pragma unroll
      for(int r=0;r<4;r++){
        const int row = q0 + g*16 + quad*4 + r;
        O[((size_t)(b*CN+row))*CE + h*CD + dt*16 + m16] = f2b(oacc[g][dt][r]*linv[r]);
      }
    }
  }
}

extern "C" void kernel_launch(void* const* d_in, const int* in_sizes, int n_in,
                              void* d_out, int out_size, void* d_ws, size_t ws_size,
                              hipStream_t stream)
{
  (void)in_sizes; (void)n_in; (void)out_size; (void)ws_size;
  const float* x     = (const float*)d_in[0];
  const float* w_qkv = (const float*)d_in[1];
  const float* b_qkv = (const float*)d_in[2];
  const float* w_proj= (const float*)d_in[3];
  const float* b_proj= (const float*)d_in[4];
  const float* g1    = (const float*)d_in[5];
  const float* be1   = (const float*)d_in[6];
  const float* g2    = (const float*)d_in[7];
  const float* be2   = (const float*)d_in[8];
  const float* w_fc1 = (const float*)d_in[9];
  const float* b_fc1 = (const float*)d_in[10];
  const float* w_fc2 = (const float*)d_in[11];
  const float* b_fc2 = (const float*)d_in[12];
  float* out = (float*)d_out;

  char* ws = (char*)d_ws;
  size_t off = 0;
  auto alloc = [&](size_t bytes)->char*{
    char* p = ws + off;
    off += (bytes + 255) & ~(size_t)255;
    return p;
  };
  bf16* wqkvT = (bf16*)alloc((size_t)3072*1024*2);  // [3E, E]
  bf16* wprojT= (bf16*)alloc((size_t)1024*1024*2);  // [E, E]
  bf16* wfc1T = (bf16*)alloc((size_t)4096*1024*2);  // [MLP, E]
  bf16* wfc2T = (bf16*)alloc((size_t)1024*4096*2);  // [E, MLP]
  bf16* h1    = (bf16*)alloc((size_t)CM*CE*2);      // LN out (reused for LN2)
  bf16* q     = (bf16*)alloc((size_t)CM*CE*2);      // [B,H,N,D]
  bf16* kk    = (bf16*)alloc((size_t)CM*CE*2);      // [B,H,N,D]
  bf16* vT    = (bf16*)alloc((size_t)CM*CE*2);      // [B,H,D,N]
  bf16* aO    = (bf16*)alloc((size_t)CM*CE*2);      // attn out [B,N,E]
  float* x2   = (float*)alloc((size_t)CM*CE*4);     // f32 trunk after proj
  bf16* hmlp  = q;  // reuse q..aO (4x8MB contiguous = 32MB) for bf16 [4096,4096]

  transpose4_k<<<12288,256,0,stream>>>(w_qkv, wqkvT, w_proj, wprojT,
                                       w_fc1, wfc1T, w_fc2, wfc2T);

  ln_k<<<CM,256,0,stream>>>(x, g1, be1, h1);
  gemm_k<EP_QKV,128><<<dim3(3072/128, CM/128),256,0,stream>>>(
      h1, wqkvT, b_qkv, nullptr, nullptr, nullptr, q, kk, vT, 1024, 3072);
  attn_k<<<dim3(CN/128, CB*CH),256,0,stream>>>(q, kk, vT, aO);
  gemm_k<EP_RES,64><<<dim3(1024/64, CM/128),256,0,stream>>>(
      aO, wprojT, b_proj, x, x2, nullptr, nullptr,nullptr,nullptr, 1024, 1024);
  ln_k<<<CM,256,0,stream>>>(x2, g2, be2, h1);
  gemm_k<EP_GELU,128><<<dim3(4096/128, CM/128),256,0,stream>>>(
      h1, wfc1T, b_fc1, nullptr, nullptr, hmlp, nullptr,nullptr,nullptr, 1024, 4096);
  gemm_k<EP_RES,64><<<dim3(1024/64, CM/128),256,0,stream>>>(
      hmlp, wfc2T, b_fc2, x2, out, nullptr, nullptr,nullptr,nullptr, 4096, 1024);
}

// Round 7
// 336.541 us; speedup vs baseline: 1.1711x; 1.0074x over previous
//
#include <hip/hip_runtime.h>
#include <hip/hip_bf16.h>
#include <cmath>

// ---------------------------------------------------------------------------
// TransformerEncoderLayer, fp32 in/out (bf16 MFMA internally), MI355X gfx950.
// Pipeline: fused weight-transpose(f32->bf16T, ONE launch) -> LN1
//           -> GEMM(qkv,scatter, Q prescaled) -> flash-attn
//           -> GEMM(proj,+x -> f32 x2) -> LN2 -> GEMM(fc1,GELU)
//           -> GEMM(fc2,+x2 -> f32 out)
// v10 = R6 (proven 339us) + attn VALU-diet (GEMMs byte-identical):
//   - Q prescaled by 0.125*log2(e) in the qkv epilogue (S linear in Q;
//     bf16 rounding relative -> exactness unchanged). attn exp = bare
//     v_exp_f32 (exp2), no per-element scale mul (-64 mul/wave-iter).
//   - Row-sum via ones-MFMA: lacc = mfma(P_frag, ones, lacc) on the idle
//     matrix pipe replaces 64 scalar li-adds/wave-iter AND the final
//     12 shuffles (MFMA C-layout lands the sum at lacc[g][r] = exactly the
//     rows this lane writes). li now sums bf16-rounded P = same values PV
//     uses -> O/li ratio more self-consistent.
// GEMM notes (R1-R6 evidence, do not revisit blindly):
//   - BN=128 (qkv/fc1): 2-buffer __syncthreads loop. Bigger tiles / 8-phase
//     raw-barrier / deep prefetch all REGRESSED (R2/R3/R4).
//   - BN=64 (proj/fc2): NBUF=3 + vmcnt(6) counted prefetch (+2us, R6).
//     fc2 sits near the LDS-bandwidth floor of the 64x32-per-wave geometry
//     (144KB LDS traffic/CU-iter ~ 1530cy vs 2190 measured).
// Attention: XCD remap (FETCH 70->12MB), K/V gl_lds swizzled source.
// ---------------------------------------------------------------------------

typedef __hip_bfloat16 bf16;
typedef __bf16 bf16x8 __attribute__((ext_vector_type(8)));
typedef __bf16 bf16x4v __attribute__((ext_vector_type(4)));
typedef float  f32x4  __attribute__((ext_vector_type(4)));

#define CB 2
#define CN 2048
#define CE 1024
#define CH 16
#define CD 64
#define CMLP 4096
#define CM (CB*CN)   // 4096 tokens

#define PS 136       // attn P-tile LDS row stride (elems)

#define QPRE 0.18033688011112042f   // 0.125 * log2(e), folded into Q
#if __has_builtin(__builtin_amdgcn_exp2f)
#define EXP2(s) __builtin_amdgcn_exp2f(s)
#else
#define EXP2(s) __expf((s)*0.69314718055994531f)
#endif

__device__ __forceinline__ float b2f(bf16 v){ return __bfloat162float(v); }
__device__ __forceinline__ bf16  f2b(float v){ return __float2bfloat16(v); }

__device__ __forceinline__ void gl_lds16(const void* g, void* l){
  __builtin_amdgcn_global_load_lds((__attribute__((address_space(1))) void*)g,
                                   (__attribute__((address_space(3))) void*)l,
                                   16, 0, 0);
}

#define FENCE asm volatile("" ::: "memory")
#define BAR   do{ FENCE; __builtin_amdgcn_s_barrier(); FENCE; }while(0)
#define VMW6  asm volatile("s_waitcnt vmcnt(6)" ::: "memory")
#define VMW0  asm volatile("s_waitcnt vmcnt(0)" ::: "memory")

// Fused weight transpose: all 4 weights in ONE launch.
// in: f32 [K,N] row-major -> out: bf16 [N,K] row-major.
// tiles: qkv 96x32=3072, proj 32x32=1024, fc1 128x32=4096, fc2 32x128=4096.
__global__ __launch_bounds__(256) void transpose4_k(
  const float* __restrict__ i0, bf16* __restrict__ o0,
  const float* __restrict__ i1, bf16* __restrict__ o1,
  const float* __restrict__ i2, bf16* __restrict__ o2,
  const float* __restrict__ i3, bf16* __restrict__ o3)
{
  __shared__ float tile[32][33];
  int t = blockIdx.x;
  const float* in; bf16* out; int K, N, nx;
  if(t < 3072){            in=i0; out=o0; K=1024; N=3072; nx=96; }
  else if(t < 4096){ t-=3072; in=i1; out=o1; K=1024; N=1024; nx=32; }
  else if(t < 8192){ t-=4096; in=i2; out=o2; K=1024; N=4096; nx=128; }
  else {             t-=8192; in=i3; out=o3; K=4096; N=1024; nx=32; }
  const int n0 = (t%nx)*32, k0 = (t/nx)*32;
  const int tx = threadIdx.x & 31;
  const int ty = threadIdx.x >> 5;   // 0..7
  #pragma unroll
  for(int i=0;i<32;i+=8) tile[ty+i][tx] = in[(size_t)(k0+ty+i)*N + n0+tx];
  __syncthreads();
  #pragma unroll
  for(int i=0;i<32;i+=8) out[(size_t)(n0+ty+i)*K + k0+tx] = f2b(tile[tx][ty+i]);
}

// LayerNorm: one row (E=1024) per 256-thread block; f32 in -> bf16 out
__global__ __launch_bounds__(256) void ln_k(const float* __restrict__ x,
                                            const float* __restrict__ g,
                                            const float* __restrict__ be,
                                            bf16* __restrict__ out){
  const int row = blockIdx.x;
  const int t = threadIdx.x;
  const float4 v4 = ((const float4*)(x + (size_t)row*CE))[t];
  float v[4] = {v4.x, v4.y, v4.z, v4.w};
  float s=0.f, s2=0.f;
  #pragma unroll
  for(int i=0;i<4;i++){ s+=v[i]; s2+=v[i]*v[i]; }
  #pragma unroll
  for(int off=32; off>0; off>>=1){ s += __shfl_down(s,off); s2 += __shfl_down(s2,off); }
  __shared__ float red[8];
  __shared__ float mu_s, rs_s;
  const int wv=t>>6, ln=t&63;
  if(ln==0){ red[wv]=s; red[4+wv]=s2; }
  __syncthreads();
  if(t==0){
    float S=red[0]+red[1]+red[2]+red[3], S2=red[4]+red[5]+red[6]+red[7];
    float mu=S/CE;
    mu_s=mu; rs_s=rsqrtf(S2/CE - mu*mu + 1e-5f);
  }
  __syncthreads();
  const float mu=mu_s, rs=rs_s;
  #pragma unroll
  for(int i=0;i<4;i++){
    int c=t*4+i;
    out[(size_t)row*CE+c] = f2b((v[i]-mu)*rs*g[c] + be[c]);
  }
}

#define EP_QKV 0
#define EP_RES 1
#define EP_GELU 2

// C = A[M,K](bf16) * BT[N,K](bf16)^T (+f32 bias; epilogue per MODE)
// Tile 128 x BN, BK=64; 4 waves, each 64 x BN/2 (MI=4, NJ=BN/32).
// Requires gridDim.y == 32 (M=4096) for the XCD remap.
template<int MODE, int BN>
__global__ __launch_bounds__(256,2) void gemm_k(
  const bf16* __restrict__ A, const bf16* __restrict__ BT,
  const float* __restrict__ bias, const float* __restrict__ res,
  float* __restrict__ Cf, bf16* __restrict__ Cb,
  bf16* __restrict__ Cq, bf16* __restrict__ Ck, bf16* __restrict__ Cv,
  int Ksz, int Nsz)
{
  constexpr int NJ = BN/32;           // B frags per wave (2 or 4)
  constexpr int NBUF = (BN==64) ? 3 : 2;
  __shared__ __align__(16) bf16 Alds[NBUF][128*64];
  __shared__ __align__(16) bf16 Blds[NBUF][BN*64];
  const int tid = threadIdx.x;
  const int wave = tid>>6, lane = tid&63;
  const int m16 = lane&15, quad = lane>>4;
  const int wi = wave>>1, wj = wave&1;

  // XCD co-location: same m-tile -> same lin%8 -> same XCD L2 holds A-tile.
  const int lin = blockIdx.x + gridDim.x*blockIdx.y;
  const int m_idx = (lin&7) + 8*((lin>>3)&3);
  const int n_idx = lin>>5;
  const size_t m0 = (size_t)m_idx*128;
  const size_t n0 = (size_t)n_idx*BN;

  f32x4 acc[4][NJ] = {};

  // staging: instr j covers 8 rows; lane -> row +lane/8, swizzled chunk
  const int srow8 = lane>>3;                   // 0..7
  const int schk  = ((lane&7)^srow8)*8;        // elem offset, XOR swizzle
  const bf16* pA = A  + (m0 + 32*wave      + srow8)*(size_t)Ksz + schk;
  const bf16* pB = BT + (n0 + (BN/4)*wave  + srow8)*(size_t)Ksz + schk;

  auto stage = [&](int buf, const bf16* gA, const bf16* gB){
    bf16* lA = &Alds[buf][wave*2048];          // 32 rows * 64 elems
    bf16* lB = &Blds[buf][wave*(BN*16)];       // BN/4 rows * 64 elems
    #pragma unroll
    for(int j=0;j<4;j++)  gl_lds16(gA + (size_t)(j*8)*Ksz, lA + j*512);
    #pragma unroll
    for(int j=0;j<NJ;j++) gl_lds16(gB + (size_t)(j*8)*Ksz, lB + j*512);
  };
  auto compute = [&](int buf){
    #pragma unroll
    for(int w=0;w<2;w++){
      const int sw = (m16&7);
      bf16x8 af[4], bfr[NJ];
      #pragma unroll
      for(int i=0;i<4;i++){
        const int row = wi*64+16*i+m16;
        af[i] = *(const bf16x8*)(&Alds[buf][row*64 + ((w*4+quad)^sw)*8]);
      }
      #pragma unroll
      for(int j=0;j<NJ;j++){
        const int row = wj*(BN/2)+16*j+m16;
        bfr[j] = *(const bf16x8*)(&Blds[buf][row*64 + ((w*4+quad)^sw)*8]);
      }
      #pragma unroll
      for(int i=0;i<4;i++)
        #pragma unroll
        for(int j=0;j<NJ;j++)
          acc[i][j] = __builtin_amdgcn_mfma_f32_16x16x32_bf16(af[i], bfr[j], acc[i][j], 0,0,0);
    }
  };

  const int kIters = Ksz/64;
  if constexpr (BN==64){
    // 3-buffer, 2-tile-ahead prefetch; counted vmcnt + raw barrier per iter.
    stage(0, pA, pB); pA += 64; pB += 64;
    stage(1, pA, pB); pA += 64; pB += 64;
    int bc = 0, bs = 2;
    for(int kb=0; kb<kIters; ++kb){
      if(kb==kIters-1){ VMW0; } else { VMW6; }   // own tile-kb loads landed
      BAR;                                        // -> all waves' tile kb
      if(kb+2<kIters){ stage(bs, pA, pB); pA += 64; pB += 64; }
      compute(bc);
      bc = (bc==2)?0:bc+1;
      bs = (bs==2)?0:bs+1;
    }
  } else {
    // Proven 2-buffer loop: ONE __syncthreads per iter (implicit vmcnt(0)
    // drain waits tile kb issued a full compute phase earlier).
    stage(0, pA, pB); pA += 64; pB += 64;
    for(int kb=0; kb<kIters; ++kb){
      __syncthreads();                  // tile kb landed; compute(kb-1) done
      if(kb+1<kIters){ stage((kb+1)&1, pA, pB); pA += 64; pB += 64; }
      compute(kb&1);                    // overlaps tile kb+1 load latency
    }
  }

  // epilogue: elem (row = m0+wi*64+16i+quad*4+r, col = n0+wj*(BN/2)+16j+m16)
  #pragma unroll
  for(int i=0;i<4;i++){
    #pragma unroll
    for(int j=0;j<NJ;j++){
      const int col = (int)n0 + wj*(BN/2) + 16*j + m16;
      const float bcol = bias[col];
      #pragma unroll
      for(int r=0;r<4;r++){
        const int row = (int)m0 + wi*64 + 16*i + quad*4 + r;
        float v = acc[i][j][r] + bcol;
        if constexpr (MODE==EP_QKV){
          const int b = row>>11, n = row&2047;
          const int which = col>>10, cc = col&1023;
          const int h = cc>>6, d = cc&63;
          if(which==0)      Cq[(((size_t)(b*CH+h))*CN+n)*CD + d] = f2b(v*QPRE);
          else if(which==1) Ck[(((size_t)(b*CH+h))*CN+n)*CD + d] = f2b(v);
          else              Cv[(((size_t)(b*CH+h))*CD+d)*CN + n] = f2b(v);
        } else if constexpr (MODE==EP_RES){
          v += res[(size_t)row*Nsz+col];
          Cf[(size_t)row*Nsz+col] = v;
        } else { // EP_GELU: tanh-form, branch-free.
          const float u2 = 1.5957691216f*(v + 0.044715f*v*v*v);
          v = v * (1.f/(1.f + __expf(-u2)));
          Cb[(size_t)row*Nsz+col] = f2b(v);
        }
      }
    }
  }
}

// Flash attention: grid (16,32) remapped so all 16 q-blocks of one (b,h)
// share lin%8 (same XCD -> K/V re-reads hit that XCD's L2; FETCH 70->12MB).
// 4 waves; wave = 32 q-rows (2 groups of 16); key tiles of 128 in LDS.
// S^T = K*Q^T (packed b64 P-stores); Q pre-scaled -> bare exp2; row-sum via
// ones-MFMA (lacc[g][r] = sum_k P[q=g*16+quad*4+r][k], no shuffles needed).
// Q,K: bf16 [B,H,N,D]; Vt: bf16 [B,H,D,N]; O: bf16 [B,N,E] (col = h*64+d)
__global__ __launch_bounds__(256,2) void attn_k(
  const bf16* __restrict__ Q, const bf16* __restrict__ Kx,
  const bf16* __restrict__ Vt, bf16* __restrict__ O)
{
  const int lin = blockIdx.x + gridDim.x*blockIdx.y;
  const int bh = (lin&7) + 8*(lin>>7);
  const int qblk = (lin>>3)&15;
  const int b = bh>>4, h = bh&15;
  const int tid = threadIdx.x;
  const int wave = tid>>6, lane = tid&63;
  const int m16 = lane&15, quad = lane>>4;
  const int sw = m16&7;
  const int q0 = qblk*128 + wave*32;

  const bf16* Qb = Q  + (size_t)bh*CN*CD;
  const bf16* Kb = Kx + (size_t)bh*CN*CD;
  const bf16* Vb = Vt + (size_t)bh*CD*CN;

  bf16x8 qf[2][2];
  #pragma unroll
  for(int g=0;g<2;g++){
    const bf16* qp = Qb + (size_t)(q0+g*16+m16)*CD + quad*8;
    qf[g][0] = *(const bf16x8*)(qp);
    qf[g][1] = *(const bf16x8*)(qp + 32);
  }

  bf16x8 onesv;
  #pragma unroll
  for(int i=0;i<8;i++) onesv[i] = (__bf16)1.0f;

  f32x4 lacc[2] = {};
  f32x4 oacc[2][4] = {};

  __shared__ __align__(16) bf16 Klds[128*64];   // 16 KB
  __shared__ __align__(16) bf16 Vlds[64*128];   // 16 KB
  __shared__ __align__(16) bf16 Plds[4][32*PS]; // 34.8 KB
  bf16* Pw = &Plds[wave][0];

  const int krow = wave*32 + (lane>>3);
  const int kchk = (lane&7) ^ (lane>>3);
  const bf16* pK = Kb + (size_t)krow*CD + kchk*8;
  const int vrow = wave*16 + (lane>>4);
  const bf16* pV[4];
  #pragma unroll
  for(int j=0;j<4;j++){
    const int ck = (lane&15) ^ ((j*4 + (lane>>4)) & 7);
    pV[j] = Vb + (size_t)(vrow + j*4)*CN + ck*8;
  }
  bf16* lK = Klds + wave*2048;
  bf16* lV = Vlds + wave*2048;

  for(int kt=0; kt<CN; kt+=128){
    __syncthreads();
    #pragma unroll
    for(int j=0;j<4;j++){
      gl_lds16(pK + (size_t)j*8*CD, lK + j*512);
      gl_lds16(pV[j],               lV + j*512);
      pV[j] += 128;
    }
    pK += (size_t)128*CD;
    __syncthreads();

    f32x4 sf0[8], sf1[8];
    #pragma unroll
    for(int f=0;f<8;f++){
      const bf16* kb = Klds + (f*16+m16)*64;
      bf16x8 k0 = *(const bf16x8*)(kb + ((quad   ^ sw)*8));
      bf16x8 k1 = *(const bf16x8*)(kb + (((quad+4)^ sw)*8));
      f32x4 t0 = {}, t1 = {};
      t0 = __builtin_amdgcn_mfma_f32_16x16x32_bf16(k0, qf[0][0], t0, 0,0,0);
      t0 = __builtin_amdgcn_mfma_f32_16x16x32_bf16(k1, qf[0][1], t0, 0,0,0);
      t1 = __builtin_amdgcn_mfma_f32_16x16x32_bf16(k0, qf[1][0], t1, 0,0,0);
      t1 = __builtin_amdgcn_mfma_f32_16x16x32_bf16(k1, qf[1][1], t1, 0,0,0);
      sf0[f]=t0; sf1[f]=t1;
    }
    #pragma unroll
    for(int f=0;f<8;f++){
      bf16x4v p0, p1;
      #pragma unroll
      for(int r=0;r<4;r++){
        p0[r] = (__bf16)EXP2(sf0[f][r]);
        p1[r] = (__bf16)EXP2(sf1[f][r]);
      }
      *(bf16x4v*)(Pw + (size_t)m16*PS       + f*16 + quad*4) = p0;
      *(bf16x4v*)(Pw + (size_t)(16+m16)*PS  + f*16 + quad*4) = p1;
    }
    asm volatile("s_waitcnt lgkmcnt(0)" ::: "memory");
    #pragma unroll
    for(int c=0;c<4;c++){
      const bf16x8 ap0 = *(const bf16x8*)(Pw + (size_t)m16*PS      + c*32 + quad*8);
      const bf16x8 ap1 = *(const bf16x8*)(Pw + (size_t)(16+m16)*PS + c*32 + quad*8);
      lacc[0] = __builtin_amdgcn_mfma_f32_16x16x32_bf16(ap0, onesv, lacc[0], 0,0,0);
      lacc[1] = __builtin_amdgcn_mfma_f32_16x16x32_bf16(ap1, onesv, lacc[1], 0,0,0);
      #pragma unroll
      for(int dt=0;dt<4;dt++){
        const int d = dt*16+m16;
        bf16x8 bv = *(const bf16x8*)(Vlds + d*128 + (((c*4+quad) ^ sw)*8));
        oacc[0][dt] = __builtin_amdgcn_mfma_f32_16x16x32_bf16(ap0, bv, oacc[0][dt], 0,0,0);
        oacc[1][dt] = __builtin_amdgcn_mfma_f32_16x16x32_bf16(ap1, bv, oacc[1][dt], 0,0,0);
      }
    }
  }
  // lacc[g][r] = row-sum for q-row g*16+quad*4+r (same value in all 16 cols)
  #pragma unroll
  for(int g=0;g<2;g++){
    float linv[4];
    #pragma unroll
    for(int r=0;r<4;r++) linv[r] = 1.f / lacc[g][r];
    #pragma unroll
    for(int dt=0;dt<4;dt++){
      #pragma unroll
      for(int r=0;r<4;r++){
        const int row = q0 + g*16 + quad*4 + r;
        O[((size_t)(b*CN+row))*CE + h*CD + dt*16 + m16] = f2b(oacc[g][dt][r]*linv[r]);
      }
    }
  }
}

extern "C" void kernel_launch(void* const* d_in, const int* in_sizes, int n_in,
                              void* d_out, int out_size, void* d_ws, size_t ws_size,
                              hipStream_t stream)
{
  (void)in_sizes; (void)n_in; (void)out_size; (void)ws_size;
  const float* x     = (const float*)d_in[0];
  const float* w_qkv = (const float*)d_in[1];
  const float* b_qkv = (const float*)d_in[2];
  const float* w_proj= (const float*)d_in[3];
  const float* b_proj= (const float*)d_in[4];
  const float* g1    = (const float*)d_in[5];
  const float* be1   = (const float*)d_in[6];
  const float* g2    = (const float*)d_in[7];
  const float* be2   = (const float*)d_in[8];
  const float* w_fc1 = (const float*)d_in[9];
  const float* b_fc1 = (const float*)d_in[10];
  const float* w_fc2 = (const float*)d_in[11];
  const float* b_fc2 = (const float*)d_in[12];
  float* out = (float*)d_out;

  char* ws = (char*)d_ws;
  size_t off = 0;
  auto alloc = [&](size_t bytes)->char*{
    char* p = ws + off;
    off += (bytes + 255) & ~(size_t)255;
    return p;
  };
  bf16* wqkvT = (bf16*)alloc((size_t)3072*1024*2);  // [3E, E]
  bf16* wprojT= (bf16*)alloc((size_t)1024*1024*2);  // [E, E]
  bf16* wfc1T = (bf16*)alloc((size_t)4096*1024*2);  // [MLP, E]
  bf16* wfc2T = (bf16*)alloc((size_t)1024*4096*2);  // [E, MLP]
  bf16* h1    = (bf16*)alloc((size_t)CM*CE*2);      // LN out (reused for LN2)
  bf16* q     = (bf16*)alloc((size_t)CM*CE*2);      // [B,H,N,D]
  bf16* kk    = (bf16*)alloc((size_t)CM*CE*2);      // [B,H,N,D]
  bf16* vT    = (bf16*)alloc((size_t)CM*CE*2);      // [B,H,D,N]
  bf16* aO    = (bf16*)alloc((size_t)CM*CE*2);      // attn out [B,N,E]
  float* x2   = (float*)alloc((size_t)CM*CE*4);     // f32 trunk after proj
  bf16* hmlp  = q;  // reuse q..aO (4x8MB contiguous = 32MB) for bf16 [4096,4096]

  transpose4_k<<<12288,256,0,stream>>>(w_qkv, wqkvT, w_proj, wprojT,
                                       w_fc1, wfc1T, w_fc2, wfc2T);

  ln_k<<<CM,256,0,stream>>>(x, g1, be1, h1);
  gemm_k<EP_QKV,128><<<dim3(3072/128, CM/128),256,0,stream>>>(
      h1, wqkvT, b_qkv, nullptr, nullptr, nullptr, q, kk, vT, 1024, 3072);
  attn_k<<<dim3(CN/128, CB*CH),256,0,stream>>>(q, kk, vT, aO);
  gemm_k<EP_RES,64><<<dim3(1024/64, CM/128),256,0,stream>>>(
      aO, wprojT, b_proj, x, x2, nullptr, nullptr,nullptr,nullptr, 1024, 1024);
  ln_k<<<CM,256,0,stream>>>(x2, g2, be2, h1);
  gemm_k<EP_GELU,128><<<dim3(4096/128, CM/128),256,0,stream>>>(
      h1, wfc1T, b_fc1, nullptr, nullptr, hmlp, nullptr,nullptr,nullptr, 1024, 4096);
  gemm_k<EP_RES,64><<<dim3(1024/64, CM/128),256,0,stream>>>(
      hmlp, wfc2T, b_fc2, x2, out, nullptr, nullptr,nullptr,nullptr, 4096, 1024);
}